// Round 19
// baseline (91.993 us; speedup 1.0000x reference)
//
#include <hip/hip_runtime.h>

#define HW 128
#define XBb 16           // byte offset of x triple-buffer (16B pad before)
#define XBf 4            // same, in floats
#define KTb 36880        // byte offset of ktab = 16 + 3*12288
#define LDS_BYTES 39952  // 36880 + 3072

typedef __attribute__((ext_vector_type(8))) short  bfrag;   // 8 bf16
typedef __attribute__((ext_vector_type(16))) float f16x;    // 32x32 accumulator
typedef __attribute__((ext_vector_type(4)))  float f4;

__device__ __forceinline__ float lrelu(float x) { return x > 0.f ? x : 0.1f * x; }

// RNE fp32 -> bf16
__device__ __forceinline__ short f2bf(float f) {
    unsigned u = __builtin_bit_cast(unsigned, f);
    u = u + 0x7FFFu + ((u >> 16) & 1u);
    return (short)(u >> 16);
}

__device__ float g_ktab[32 * 768];                // [b][m][a][g][j2][12] att-folded taps
__device__ short g_whi[4096];                     // conv_w bf16 (RNE), [o*64+c]

// ---------- prep: b<32 -> att-folded kernels; b==32 -> W bf16 ----------
__global__ __launch_bounds__(64) void dgfem_prep(
    const float* __restrict__ v, const float* __restrict__ ca_w1,
    const float* __restrict__ ca_w2, const float* __restrict__ k_w1,
    const float* __restrict__ k_w2, const float* __restrict__ conv_w)
{
    const int b = blockIdx.x;
    const int t = threadIdx.x;           // 64 threads

    if (b == 32) {
        for (int i = t; i < 4096; i += 64) g_whi[i] = f2bf(conv_w[i]);
        return;
    }

    __shared__ float vb[64], t1[8], att[64], t2[64];
    vb[t] = v[b * 64 + t];
    __syncthreads();

    if (t < 8) {
        float s = 0.f;
        for (int j = 0; j < 64; ++j) s += vb[j] * ca_w1[t * 64 + j];
        t1[t] = lrelu(s);
    }
    {
        float s = 0.f;
        for (int j = 0; j < 64; ++j) s += vb[j] * k_w1[t * 64 + j];
        t2[t] = lrelu(s);
    }
    __syncthreads();
    {
        float s = 0.f;
        for (int i = 0; i < 8; ++i) s += t1[i] * ca_w2[t * 8 + i];
        att[t] = 1.f / (1.f + expf(-s));
    }
    __syncthreads();
    // fold att[c]; layout [m][a][g][j2][12], c = m*16 + g*8 + a*4 + j2
    for (int r = t; r < 576; r += 64) {
        int c = r / 9, tp = r - c * 9;
        float s = 0.f;
        for (int j = 0; j < 64; ++j) s += t2[j] * k_w2[r * 64 + j];
        int m = c >> 4, g = (c >> 3) & 1, a = (c >> 2) & 1, j2 = c & 3;
        g_ktab[b * 768 + (((m * 2 + a) * 2 + g) * 4 + j2) * 12 + tp] = s * att[c];
    }
}

__global__ __launch_bounds__(256) void dgfem_main(
    const float* __restrict__ x0, const float* __restrict__ conv_b,
    float* __restrict__ out)
{
    const int t  = threadIdx.x;          // 256 threads = 4 waves
    const int w  = t >> 6;
    const int l  = t & 63;
    const int g  = l >> 5;               // k-half
    const int ln = l & 31;
    const int px = w * 32 + ln;

    // XCD swizzle (4096 % 8 == 0, bijective)
    const int bid  = blockIdx.x;
    const int orig = (bid & 7) * 512 + (bid >> 3);
    const int b    = orig >> 7;          // 0..31
    const int gy   = orig & 127;         // output row

    __shared__ __align__(16) char lds[LDS_BYTES];
    float* ldsf = (float*)lds;

    // stage ktab with row masks folded in (masked row taps -> 0)
    {
        const float* ksrc = g_ktab + b * 768;
        const float rm0 = (gy > 0)   ? 1.f : 0.f;
        const float rm2 = (gy < 127) ? 1.f : 0.f;
        for (int i = t; i < 768; i += 256) {
            int tp = i % 12;
            float val = (tp < 9) ? ksrc[i] : 0.f;
            float rm = (tp < 3) ? rm0 : ((tp < 6) ? 1.f : rm2);
            *(float*)(lds + KTb + i * 4) = val * rm;
        }
    }

    // preload ALL W fragments into registers (keeps round vmcnt stream pure-stage)
    bfrag wh0[4], wh1[4];
    {
        const char* whb = (const char*)g_whi + ln * 128 + g * 16;
        #pragma unroll
        for (int m = 0; m < 4; ++m) {
            wh0[m] = *(const bfrag*)(whb + m * 32);
            wh1[m] = *(const bfrag*)(whb + m * 32 + 4096);
        }
    }

    // per-lane clamped source offsets: 3 sweeps of 1 KB per wave cover 12 KB/round
    const int doff = w * 1024 + l * 16;
    int inv0, inv1, inv2;
    {
        #pragma unroll
        for (int q = 0; q < 3; ++q) {
            int F      = q * 4096 + doff;
            int slot   = F / 1536;
            int within = F - slot * 1536;
            int rowq   = gy - 1 + (within >> 9);
            int crow   = min(max(rowq, 0), 127);
            int gs = slot >> 2, j2s = slot & 3;
            int iv = (gs * 8 + j2s) * 65536 + crow * 512 + (within & 511);
            if (q == 0) inv0 = iv; else if (q == 1) inv1 = iv; else inv2 = iv;
        }
    }

    const char* xb = (const char*)x0 + ((size_t)b << 22);

    // stage 8 channels (c = m*16 + gs*8 + a*4 + j2s) x 3 row-slots into buffer sel
    #define STAGE(rr_, sel_)                                                   \
    {                                                                          \
        const char* srcb = xb + ((size_t)(((rr_) >> 1) * 16 + ((rr_) & 1) * 4) << 16); \
        char* dstb = lds + XBb + (sel_) * 12288 + doff;                        \
        __builtin_amdgcn_global_load_lds(                                      \
            (const __attribute__((address_space(1))) unsigned*)(srcb + inv0),  \
            (__attribute__((address_space(3))) unsigned*)(dstb), 16, 0, 0);    \
        __builtin_amdgcn_global_load_lds(                                      \
            (const __attribute__((address_space(1))) unsigned*)(srcb + inv1),  \
            (__attribute__((address_space(3))) unsigned*)(dstb + 4096), 16, 0, 0); \
        __builtin_amdgcn_global_load_lds(                                      \
            (const __attribute__((address_space(1))) unsigned*)(srcb + inv2),  \
            (__attribute__((address_space(3))) unsigned*)(dstb + 8192), 16, 0, 0); \
    }

    f16x acc0, acc1;
    #pragma unroll
    for (int i = 0; i < 16; ++i) { acc0[i] = 0.f; acc1[i] = 0.f; }

    const float mLf = (px > 0)   ? 1.f : 0.f;
    const float mRf = (px < 127) ? 1.f : 0.f;

    bfrag yh;

    // prologue: ktab visible to all; then 2 stages in flight, wait for the 1st
    __syncthreads();
    STAGE(0, 0);
    STAGE(1, 1);
    asm volatile("s_waitcnt vmcnt(3)" ::: "memory");
    __builtin_amdgcn_s_barrier();
    __builtin_amdgcn_sched_barrier(0);

    // ROUND rr: consume buf[rr%3]; prefetch STAGE(rr+2); counted-vmcnt barrier
    #define ROUND(rr_, a_, m_, sel_)                                           \
    {                                                                          \
        if ((rr_) < 6) STAGE((rr_) + 2, ((rr_) + 2) % 3);                      \
        const float* xbase = ldsf + (XBf + (sel_) * 3072 + g * 1536 + px - 1); \
        const char*  kb = lds + KTb + ((rr_) * 8 + g * 4) * 48;                \
        _Pragma("unroll")                                                      \
        for (int j2 = 0; j2 < 4; ++j2) {                                       \
            const f4* kf = (const f4*)(kb + j2 * 48);                          \
            f4 kA = kf[0], kB = kf[1], kC = kf[2];                             \
            const float* bA = xbase + j2 * 384;                                \
            float xL0 = bA[0]   * mLf, xC0 = bA[1],   xR0 = bA[2]   * mRf;     \
            float xL1 = bA[128] * mLf, xC1 = bA[129], xR1 = bA[130] * mRf;     \
            float xL2 = bA[256] * mLf, xC2 = bA[257], xR2 = bA[258] * mRf;     \
            float aY = fmaf(kA.x, xL0, fmaf(kA.y, xC0, kA.z * xR0))            \
                     + fmaf(kA.w, xL1, fmaf(kB.x, xC1, kB.y * xR1))            \
                     + fmaf(kB.z, xL2, fmaf(kB.w, xC2, kC.x * xR2));           \
            yh[(a_) * 4 + j2] = f2bf(lrelu(aY));                               \
        }                                                                      \
        if (a_) {                                                              \
            acc0 = __builtin_amdgcn_mfma_f32_32x32x16_bf16(wh0[m_], yh, acc0, 0, 0, 0); \
            acc1 = __builtin_amdgcn_mfma_f32_32x32x16_bf16(wh1[m_], yh, acc1, 0, 0, 0); \
        }                                                                      \
        if ((rr_) < 7) {                                                       \
            if ((rr_) < 6) { asm volatile("s_waitcnt vmcnt(3)" ::: "memory"); }\
            else           { asm volatile("s_waitcnt vmcnt(0)" ::: "memory"); }\
            __builtin_amdgcn_s_barrier();                                      \
            __builtin_amdgcn_sched_barrier(0);                                 \
        }                                                                      \
    }

    ROUND(0, 0, 0, 0);
    ROUND(1, 1, 0, 1);
    ROUND(2, 0, 1, 2);
    ROUND(3, 1, 1, 0);
    ROUND(4, 0, 2, 1);
    ROUND(5, 1, 2, 2);
    ROUND(6, 0, 3, 0);
    ROUND(7, 1, 3, 1);

    #undef ROUND
    #undef STAGE

    // epilogue: D layout col=lane&31, row=(reg&3)+8*(reg>>2)+4*(lane>>5)  [verified 9x]
    float* ob = out + ((size_t)b << 20) + (size_t)gy * HW + px;
    #pragma unroll
    for (int q = 0; q < 4; ++q) {
        const int obase = 8 * q + 4 * g;
        float4 bv0 = *(const float4*)&conv_b[obase];
        float4 bv1 = *(const float4*)&conv_b[32 + obase];
        const float* b0f = (const float*)&bv0;
        const float* b1f = (const float*)&bv1;
        #pragma unroll
        for (int r2 = 0; r2 < 4; ++r2) {
            ob[(size_t)(obase + r2) * 16384]      = acc0[q * 4 + r2] + b0f[r2];
            ob[(size_t)(32 + obase + r2) * 16384] = acc1[q * 4 + r2] + b1f[r2];
        }
    }
}

extern "C" void kernel_launch(void* const* d_in, const int* in_sizes, int n_in,
                              void* d_out, int out_size, void* d_ws, size_t ws_size,
                              hipStream_t stream) {
    const float* x0     = (const float*)d_in[0];
    const float* v      = (const float*)d_in[1];
    const float* ca_w1  = (const float*)d_in[2];
    const float* ca_w2  = (const float*)d_in[3];
    const float* k_w1   = (const float*)d_in[4];
    const float* k_w2   = (const float*)d_in[5];
    const float* conv_w = (const float*)d_in[6];
    const float* conv_b = (const float*)d_in[7];
    float* outp = (float*)d_out;

    dgfem_prep<<<dim3(33), dim3(64), 0, stream>>>(v, ca_w1, ca_w2, k_w1, k_w2, conv_w);
    dgfem_main<<<dim3(4096), dim3(256), 0, stream>>>(x0, conv_b, outp);
}

// Round 20
// 80.086 us; speedup vs baseline: 1.1487x; 1.1487x over previous
//
#include <hip/hip_runtime.h>

#define HW 128
#define XBb 16           // byte offset of x double-buffer (16B pad before)
#define XBf 4            // same, in floats
#define KTb 24592        // byte offset of ktab = 16 + 2*12288
#define LDS_BYTES 27664  // 24592 + 3072

typedef __attribute__((ext_vector_type(8))) short  bfrag;   // 8 bf16
typedef __attribute__((ext_vector_type(16))) float f16x;    // 32x32 accumulator
typedef __attribute__((ext_vector_type(4)))  float f4;

__device__ __forceinline__ float lrelu(float x) { return x > 0.f ? x : 0.1f * x; }

// RNE fp32 -> bf16
__device__ __forceinline__ short f2bf(float f) {
    unsigned u = __builtin_bit_cast(unsigned, f);
    u = u + 0x7FFFu + ((u >> 16) & 1u);
    return (short)(u >> 16);
}

__device__ float g_ktab[32 * 768];                // [b][m][a][g][j2][12] att-folded taps
__device__ short g_whi[4096];                     // conv_w bf16 (RNE), [o*64+c]

// ---------- prep: b<32 -> att-folded kernels; b==32 -> W bf16 ----------
__global__ __launch_bounds__(64) void dgfem_prep(
    const float* __restrict__ v, const float* __restrict__ ca_w1,
    const float* __restrict__ ca_w2, const float* __restrict__ k_w1,
    const float* __restrict__ k_w2, const float* __restrict__ conv_w)
{
    const int b = blockIdx.x;
    const int t = threadIdx.x;           // 64 threads

    if (b == 32) {
        for (int i = t; i < 4096; i += 64) g_whi[i] = f2bf(conv_w[i]);
        return;
    }

    __shared__ float vb[64], t1[8], att[64], t2[64];
    vb[t] = v[b * 64 + t];
    __syncthreads();

    if (t < 8) {
        float s = 0.f;
        for (int j = 0; j < 64; ++j) s += vb[j] * ca_w1[t * 64 + j];
        t1[t] = lrelu(s);
    }
    {
        float s = 0.f;
        for (int j = 0; j < 64; ++j) s += vb[j] * k_w1[t * 64 + j];
        t2[t] = lrelu(s);
    }
    __syncthreads();
    {
        float s = 0.f;
        for (int i = 0; i < 8; ++i) s += t1[i] * ca_w2[t * 8 + i];
        att[t] = 1.f / (1.f + expf(-s));
    }
    __syncthreads();
    // fold att[c]; layout [m][a][g][j2][12], c = m*16 + g*8 + a*4 + j2
    for (int r = t; r < 576; r += 64) {
        int c = r / 9, tp = r - c * 9;
        float s = 0.f;
        for (int j = 0; j < 64; ++j) s += t2[j] * k_w2[r * 64 + j];
        int m = c >> 4, g = (c >> 3) & 1, a = (c >> 2) & 1, j2 = c & 3;
        g_ktab[b * 768 + (((m * 2 + a) * 2 + g) * 4 + j2) * 12 + tp] = s * att[c];
    }
}

__global__ __launch_bounds__(256)
__attribute__((amdgpu_waves_per_eu(8)))
void dgfem_main(
    const float* __restrict__ x0, const float* __restrict__ conv_b,
    float* __restrict__ out)
{
    const int t  = threadIdx.x;          // 256 threads = 4 waves
    const int w  = t >> 6;
    const int l  = t & 63;
    const int g  = l >> 5;               // k-half
    const int ln = l & 31;
    const int px = w * 32 + ln;

    // XCD swizzle (4096 % 8 == 0, bijective)
    const int bid  = blockIdx.x;
    const int orig = (bid & 7) * 512 + (bid >> 3);
    const int b    = orig >> 7;          // 0..31
    const int gy   = orig & 127;         // output row

    __shared__ __align__(16) char lds[LDS_BYTES];
    float* ldsf = (float*)lds;

    // stage ktab with row masks folded in (masked row taps -> 0)
    {
        const float* ksrc = g_ktab + b * 768;
        const float rm0 = (gy > 0)   ? 1.f : 0.f;
        const float rm2 = (gy < 127) ? 1.f : 0.f;
        for (int i = t; i < 768; i += 256) {
            int tp = i % 12;
            float val = (tp < 9) ? ksrc[i] : 0.f;
            float rm = (tp < 3) ? rm0 : ((tp < 6) ? 1.f : rm2);
            *(float*)(lds + KTb + i * 4) = val * rm;
        }
    }

    // per-lane clamped source offsets: 3 sweeps of 1 KB per wave cover 12 KB/round
    // slot = gs*4+j2s (1536 B each = 3 row-slots), channel = base + gs*8 + j2s
    const int doff = w * 1024 + l * 16;  // this lane's dst offset pattern base
    int inv0, inv1, inv2;
    {
        #pragma unroll
        for (int q = 0; q < 3; ++q) {
            int F      = q * 4096 + doff;
            int slot   = F / 1536;
            int within = F - slot * 1536;
            int rowq   = gy - 1 + (within >> 9);
            int crow   = min(max(rowq, 0), 127);
            int gs = slot >> 2, j2s = slot & 3;
            int iv = (gs * 8 + j2s) * 65536 + crow * 512 + (within & 511);
            if (q == 0) inv0 = iv; else if (q == 1) inv1 = iv; else inv2 = iv;
        }
    }

    const char* xb = (const char*)x0 + ((size_t)b << 22);

    // stage 8 channels (c = m*16 + gs*8 + a*4 + j2s) x 3 row-slots, dbl-buffered
    #define STAGE(rr_, sel_)                                                   \
    {                                                                          \
        const char* srcb = xb + ((size_t)(((rr_) >> 1) * 16 + ((rr_) & 1) * 4) << 16); \
        char* dstb = lds + XBb + (sel_) * 12288 + doff;                        \
        __builtin_amdgcn_global_load_lds(                                      \
            (const __attribute__((address_space(1))) unsigned*)(srcb + inv0),  \
            (__attribute__((address_space(3))) unsigned*)(dstb), 16, 0, 0);    \
        __builtin_amdgcn_global_load_lds(                                      \
            (const __attribute__((address_space(1))) unsigned*)(srcb + inv1),  \
            (__attribute__((address_space(3))) unsigned*)(dstb + 4096), 16, 0, 0); \
        __builtin_amdgcn_global_load_lds(                                      \
            (const __attribute__((address_space(1))) unsigned*)(srcb + inv2),  \
            (__attribute__((address_space(3))) unsigned*)(dstb + 8192), 16, 0, 0); \
    }

    f16x acc0, acc1;
    #pragma unroll
    for (int i = 0; i < 16; ++i) { acc0[i] = 0.f; acc1[i] = 0.f; }

    const float mLf = (px > 0)   ? 1.f : 0.f;
    const float mRf = (px < 127) ? 1.f : 0.f;

    bfrag yh;

    STAGE(0, 0);
    __syncthreads();

    #define ROUND(rr_, a_, m_, sel_)                                           \
    {                                                                          \
        if ((rr_) < 7) STAGE((rr_) + 1, (sel_) ^ 1);                           \
        const float* xbase = ldsf + (XBf + (sel_) * 3072 + g * 1536 + px - 1); \
        const char*  kb = lds + KTb + ((rr_) * 8 + g * 4) * 48;                \
        _Pragma("unroll")                                                      \
        for (int j2 = 0; j2 < 4; ++j2) {                                       \
            const f4* kf = (const f4*)(kb + j2 * 48);                          \
            f4 kA = kf[0], kB = kf[1], kC = kf[2];                             \
            const float* bA = xbase + j2 * 384;                                \
            float xL0 = bA[0]   * mLf, xC0 = bA[1],   xR0 = bA[2]   * mRf;     \
            float xL1 = bA[128] * mLf, xC1 = bA[129], xR1 = bA[130] * mRf;     \
            float xL2 = bA[256] * mLf, xC2 = bA[257], xR2 = bA[258] * mRf;     \
            float aY = fmaf(kA.x, xL0, fmaf(kA.y, xC0, kA.z * xR0))            \
                     + fmaf(kA.w, xL1, fmaf(kB.x, xC1, kB.y * xR1))            \
                     + fmaf(kB.z, xL2, fmaf(kB.w, xC2, kC.x * xR2));           \
            yh[(a_) * 4 + j2] = f2bf(lrelu(aY));                               \
        }                                                                      \
        if (a_) {                                                              \
            const char* whb = (const char*)g_whi + ln * 128 + g * 16 + (m_) * 32; \
            bfrag whi0 = *(const bfrag*)(whb);                                 \
            bfrag whi1 = *(const bfrag*)(whb + 4096);                          \
            acc0 = __builtin_amdgcn_mfma_f32_32x32x16_bf16(whi0, yh, acc0, 0, 0, 0); \
            acc1 = __builtin_amdgcn_mfma_f32_32x32x16_bf16(whi1, yh, acc1, 0, 0, 0); \
        }                                                                      \
        if ((rr_) < 7) __syncthreads();                                        \
    }

    ROUND(0, 0, 0, 0);
    ROUND(1, 1, 0, 1);
    ROUND(2, 0, 1, 0);
    ROUND(3, 1, 1, 1);
    ROUND(4, 0, 2, 0);
    ROUND(5, 1, 2, 1);
    ROUND(6, 0, 3, 0);
    ROUND(7, 1, 3, 1);

    #undef ROUND
    #undef STAGE

    // epilogue: D layout col=lane&31, row=(reg&3)+8*(reg>>2)+4*(lane>>5)  [verified 9x]
    float* ob = out + ((size_t)b << 20) + (size_t)gy * HW + px;
    #pragma unroll
    for (int q = 0; q < 4; ++q) {
        const int obase = 8 * q + 4 * g;
        float4 bv0 = *(const float4*)&conv_b[obase];
        float4 bv1 = *(const float4*)&conv_b[32 + obase];
        const float* b0f = (const float*)&bv0;
        const float* b1f = (const float*)&bv1;
        #pragma unroll
        for (int r2 = 0; r2 < 4; ++r2) {
            ob[(size_t)(obase + r2) * 16384]      = acc0[q * 4 + r2] + b0f[r2];
            ob[(size_t)(32 + obase + r2) * 16384] = acc1[q * 4 + r2] + b1f[r2];
        }
    }
}

extern "C" void kernel_launch(void* const* d_in, const int* in_sizes, int n_in,
                              void* d_out, int out_size, void* d_ws, size_t ws_size,
                              hipStream_t stream) {
    const float* x0     = (const float*)d_in[0];
    const float* v      = (const float*)d_in[1];
    const float* ca_w1  = (const float*)d_in[2];
    const float* ca_w2  = (const float*)d_in[3];
    const float* k_w1   = (const float*)d_in[4];
    const float* k_w2   = (const float*)d_in[5];
    const float* conv_w = (const float*)d_in[6];
    const float* conv_b = (const float*)d_in[7];
    float* outp = (float*)d_out;

    dgfem_prep<<<dim3(33), dim3(64), 0, stream>>>(v, ca_w1, ca_w2, k_w1, k_w2, conv_w);
    dgfem_main<<<dim3(4096), dim3(256), 0, stream>>>(x0, conv_b, outp);
}